// Round 2
// baseline (1926.416 us; speedup 1.0000x reference)
//
#include <hip/hip_runtime.h>
#include <hip/hip_bf16.h>

typedef __hip_bfloat16 bf16;

#define HH 128  // hidden dim, fixed by the model

__device__ __forceinline__ float b2f(bf16 v) { return __bfloat162float(v); }

// dtype-adaptive scalar load/store (f32 flag decided at runtime from probe)
__device__ __forceinline__ float loadf(const void* p, long long i, bool f32) {
  return f32 ? ((const float*)p)[i] : b2f(((const bf16*)p)[i]);
}
__device__ __forceinline__ void storef(void* p, long long i, bool f32, float v) {
  if (f32) ((float*)p)[i] = v;
  else     ((bf16*)p)[i] = __float2bfloat16(v);
}
// mode: 0 = bf16 always, 1 = f32 always, 2 = follow runtime flag
__device__ __forceinline__ bool resolve(int mode, int flag) {
  return mode == 1 || (mode == 2 && flag != 0);
}

// ------------------------------------------------------------------ dtype probe
// Read 256 elements of W1_ct_l as bf16. True bf16 weights are |w| <~ 0.3.
// If the underlying data is fp32, the even 16-bit halves are ~uniform random;
// P(all 128 of them decode to |v|<100) ~ 1e-35 -> flag=1 means fp32.
__global__ void probe_kernel(const void* __restrict__ w, int* __restrict__ flag) {
  int j = threadIdx.x;
  bool bad = false;
  for (int k = 0; k < 4; ++k) {
    float v = b2f(((const bf16*)w)[j * 4 + k]);
    if (!(fabsf(v) < 100.0f)) bad = true;  // catches NaN/Inf too
  }
  if (__ballot(bad) != 0ull && j == 0) flag[0] = 1;
}

// ---------------------------------------------------------------- degree count
__global__ void count_deg_kernel(const int* __restrict__ dst,
                                 float* __restrict__ cnt, int E) {
  int i = blockIdx.x * blockDim.x + threadIdx.x;
  if (i < E) unsafeAtomicAdd(&cnt[dst[i]], 1.0f);
}

// cnt -> 1/max(cnt,1) in place
__global__ void recip_kernel(float* __restrict__ c, int n) {
  int i = blockIdx.x * blockDim.x + threadIdx.x;
  if (i < n) c[i] = 1.0f / fmaxf(c[i], 1.0f);
}

// ------------------------------------------------- edge-parallel gather+scatter
// agg[dst[e]*D + d] += x[src[e]*D + d], D = 1<<shift, thread per (e,d)
__global__ void edge_agg_kernel(const int* __restrict__ src,
                                const int* __restrict__ dst,
                                const void* __restrict__ x,
                                float* __restrict__ agg,
                                const int* __restrict__ flag,
                                int E, int shift, int xmode) {
  long long i = (long long)blockIdx.x * blockDim.x + threadIdx.x;
  long long total = (long long)E << shift;
  if (i >= total) return;
  bool f32 = resolve(xmode, *flag);
  int e = (int)(i >> shift);
  int d = (int)(i & ((1 << shift) - 1));
  int s = src[e];
  int t = dst[e];
  unsafeAtomicAdd(&agg[((long long)t << shift) + d],
                  loadf(x, ((long long)s << shift) + d, f32));
}

// ------------------------------------------- fused SAGE linear (+bias, +relu)
// out[row, j] = maybe_relu( sum_k mean[k]*Wl[k,j] + bias[j] + sum_k x[k]*Wr[k,j] )
// block = 128 threads (one per output col), 4 rows per block.
template <bool WF32>
__device__ __forceinline__ float sage_dot(const float* __restrict__ s_m,
                                          const float* __restrict__ s_x,
                                          const void* __restrict__ Wl,
                                          const void* __restrict__ Wr,
                                          int Da, int Ds, int j, float acc) {
  for (int k = 0; k < Da; ++k)
    acc = fmaf(s_m[k], loadf(Wl, (long long)k * HH + j, WF32), acc);
  for (int k = 0; k < Ds; ++k)
    acc = fmaf(s_x[k], loadf(Wr, (long long)k * HH + j, WF32), acc);
  return acc;
}

__global__ __launch_bounds__(128) void sage_linear_kernel(
    const float* __restrict__ agg, const float* __restrict__ inv,
    const void* __restrict__ xself,
    const void* __restrict__ Wl, const void* __restrict__ bias,
    const void* __restrict__ Wr,
    void* __restrict__ out, long long out_base, const int* __restrict__ flag,
    int n, int Da, int Ds, int do_relu, int xmode, int outmode) {
  __shared__ float s_m[HH];
  __shared__ float s_x[HH];
  int fl = *flag;
  bool xf32 = resolve(xmode, fl);
  bool of32 = resolve(outmode, fl);
  bool wf32 = fl != 0;
  int j = threadIdx.x;
  int row0 = blockIdx.x * 4;
  for (int r = 0; r < 4; ++r) {
    int row = row0 + r;
    if (row >= n) return;  // uniform across block
    if (j < Da) s_m[j] = agg[(long long)row * Da + j] * inv[row];
    if (j < Ds) s_x[j] = loadf(xself, (long long)row * Ds + j, xf32);
    __syncthreads();
    float acc = loadf(bias, j, wf32);
    acc = wf32 ? sage_dot<true>(s_m, s_x, Wl, Wr, Da, Ds, j, acc)
               : sage_dot<false>(s_m, s_x, Wl, Wr, Da, Ds, j, acc);
    if (do_relu) acc = fmaxf(acc, 0.f);
    storef(out, out_base + (long long)row * HH + j, of32, acc);
    __syncthreads();
  }
}

// --------------------------------------------------- decoder: relu(z@Wd1+b)@Wd2+b
// one 64-thread wave per row; z lives in d_out (dtype follows flag)
template <bool WF32>
__device__ __forceinline__ float dec_dot(const float* __restrict__ s,
                                         const void* __restrict__ W,
                                         int K, int j, float acc) {
  for (int k = 0; k < K; ++k)
    acc = fmaf(s[k], loadf(W, (long long)k * 64 + j, WF32), acc);
  return acc;
}

__global__ __launch_bounds__(64) void decoder_kernel(
    const void* __restrict__ zbuf, long long z_base,
    const void* __restrict__ Wd1, const void* __restrict__ bd1,
    const void* __restrict__ Wd2, const void* __restrict__ bd2,
    void* __restrict__ out, const int* __restrict__ flag, int n) {
  __shared__ float s_z[HH];
  __shared__ float s_t[64];
  int fl = *flag;
  bool f32 = fl != 0;
  int row = blockIdx.x;
  if (row >= n) return;
  int j = threadIdx.x;
  s_z[j]      = loadf(zbuf, z_base + (long long)row * HH + j, f32);
  s_z[j + 64] = loadf(zbuf, z_base + (long long)row * HH + 64 + j, f32);
  __syncthreads();
  float acc = loadf(bd1, j, f32);
  acc = f32 ? dec_dot<true>(s_z, Wd1, 128, j, acc)
            : dec_dot<false>(s_z, Wd1, 128, j, acc);
  s_t[j] = fmaxf(acc, 0.f);
  __syncthreads();
  float acc2 = loadf(bd2, j, f32);
  acc2 = f32 ? dec_dot<true>(s_t, Wd2, 64, j, acc2)
             : dec_dot<false>(s_t, Wd2, 64, j, acc2);
  storef(out, (long long)row * 64 + j, f32, acc2);
}

extern "C" void kernel_launch(void* const* d_in, const int* in_sizes, int n_in,
                              void* d_out, int out_size, void* d_ws,
                              size_t ws_size, hipStream_t stream) {
  const void* x_txn = d_in[0];
  const void* x_cli = d_in[1];
  const int* ct_src = (const int*)d_in[2];
  const int* ct_dst = (const int*)d_in[3];
  const int* tc_src = (const int*)d_in[4];
  const int* tc_dst = (const int*)d_in[5];
  const void* W1ctl = d_in[6];
  const void* b1ct  = d_in[7];
  const void* W1ctr = d_in[8];
  const void* W1tcl = d_in[9];
  const void* b1tc  = d_in[10];
  const void* W1tcr = d_in[11];
  const void* W2ctl = d_in[12];
  const void* b2ct  = d_in[13];
  const void* W2ctr = d_in[14];
  const void* W2tcl = d_in[15];
  const void* b2tc  = d_in[16];
  const void* W2tcr = d_in[17];
  const void* Wd1   = d_in[18];
  const void* bd1   = d_in[19];
  const void* Wd2   = d_in[20];
  const void* bd2   = d_in[21];

  const int E = in_sizes[2];  // 600000
  const int NT = 100000, NC = 20000;

  // ---- workspace layout (overlapped: agg1 and agg2 share one region) ----
  // [flag(4 floats) | cnt_ct NT | cnt_tc NC | AGG (NT*128+NC*128 floats) | H ]
  float* wsf = (float*)d_ws;
  int*   flag   = (int*)d_ws;
  float* cnt_ct = wsf + 4;
  float* cnt_tc = cnt_ct + NT;
  float* aggb   = cnt_tc + NC;
  const size_t AGGF = (size_t)NT * 128 + (size_t)NC * 128;  // 15.36M floats
  float* agg1_ct = aggb;
  float* agg1_tc = aggb + (size_t)NT * 32;
  float* agg2_ct = aggb;
  float* agg2_tc = aggb + (size_t)NT * 128;
  char* hb = (char*)(aggb + AGGF);
  size_t head_floats = (size_t)4 + NT + NC + AGGF;
  size_t need_f32_h = (head_floats + AGGF) * sizeof(float);  // ~123.4 MB
  bool h_f32 = ws_size >= need_f32_h;
  size_t hesz = h_f32 ? 4 : 2;
  void* h_txn = hb;
  void* h_cli = hb + (size_t)NT * 128 * hesz;
  int hmode = h_f32 ? 1 : 0;

  // zero: flag + counts + layer-1 agg portion of AGG region
  size_t z1 = ((size_t)4 + NT + NC + (size_t)NT * 32 + (size_t)NC * 64) * 4;
  hipMemsetAsync(d_ws, 0, z1, stream);

  const int tb = 256;
  probe_kernel<<<1, 64, 0, stream>>>(W1ctl, flag);
  count_deg_kernel<<<(E + tb - 1) / tb, tb, 0, stream>>>(ct_dst, cnt_ct, E);
  count_deg_kernel<<<(E + tb - 1) / tb, tb, 0, stream>>>(tc_dst, cnt_tc, E);
  recip_kernel<<<(NT + NC + tb - 1) / tb, tb, 0, stream>>>(cnt_ct, NT + NC);

  auto launch_agg = [&](const int* s, const int* d, const void* x, float* agg,
                        int shift, int xmode) {
    long long total = (long long)E << shift;
    int blocks = (int)((total + tb - 1) / tb);
    edge_agg_kernel<<<blocks, tb, 0, stream>>>(s, d, x, agg, flag, E, shift, xmode);
  };

  // ---- layer 1 ----
  launch_agg(ct_src, ct_dst, x_cli, agg1_ct, 5, 2);  // client(32) -> txn
  launch_agg(tc_src, tc_dst, x_txn, agg1_tc, 6, 2);  // txn(64)    -> client

  sage_linear_kernel<<<(NT + 3) / 4, 128, 0, stream>>>(
      agg1_ct, cnt_ct, x_txn, W1ctl, b1ct, W1ctr, h_txn, 0, flag,
      NT, 32, 64, /*relu=*/1, /*xmode=*/2, /*outmode=*/hmode);
  sage_linear_kernel<<<(NC + 3) / 4, 128, 0, stream>>>(
      agg1_tc, cnt_tc, x_cli, W1tcl, b1tc, W1tcr, h_cli, 0, flag,
      NC, 64, 32, 1, 2, hmode);

  // re-zero the shared AGG region for layer 2
  hipMemsetAsync(aggb, 0, AGGF * sizeof(float), stream);

  // ---- layer 2 ----
  launch_agg(ct_src, ct_dst, h_cli, agg2_ct, 7, hmode);  // h_cli(128) -> txn
  launch_agg(tc_src, tc_dst, h_txn, agg2_tc, 7, hmode);  // h_txn(128) -> client

  const long long ztxn_base = (long long)NT * 64;          // elements into d_out
  const long long zcli_base = (long long)NT * 64 + (long long)NT * 128;

  sage_linear_kernel<<<(NT + 3) / 4, 128, 0, stream>>>(
      agg2_ct, cnt_ct, h_txn, W2ctl, b2ct, W2ctr, d_out, ztxn_base, flag,
      NT, 128, 128, /*relu=*/0, /*xmode=*/hmode, /*outmode=*/2);
  sage_linear_kernel<<<(NC + 3) / 4, 128, 0, stream>>>(
      agg2_tc, cnt_tc, h_cli, W2tcl, b2tc, W2tcr, d_out, zcli_base, flag,
      NC, 128, 128, 0, hmode, 2);

  // ---- decoder ----
  decoder_kernel<<<NT, 64, 0, stream>>>(d_out, ztxn_base, Wd1, bd1, Wd2, bd2,
                                        d_out, flag, NT);
}

// Round 6
// 1171.232 us; speedup vs baseline: 1.6448x; 1.6448x over previous
//
#include <hip/hip_runtime.h>
#include <hip/hip_bf16.h>

typedef __hip_bfloat16 bf16;
typedef unsigned int uint;
typedef unsigned short ushort;
typedef __attribute__((ext_vector_type(8))) short short8;   // 8 bf16 = 4 VGPR
typedef __attribute__((ext_vector_type(4))) float float4v;  // MFMA acc

__device__ __forceinline__ ushort f2bu(float v) {
  union { bf16 h; ushort u; } x;
  x.h = __float2bfloat16(v);
  return x.u;
}

// ---------------- degree count (fp32 atomics, R2-validated) ----------------
__global__ void count_deg_kernel(const int* __restrict__ dst, float* __restrict__ cnt,
                                 int E, int n) {
  int i = blockIdx.x * 256 + threadIdx.x;
  if (i < E) {
    int d = dst[i];
    if ((unsigned)d < (unsigned)n) unsafeAtomicAdd(&cnt[d], 1.0f);
  }
}

// in-place: c -> 1/max(c,1)
__global__ void recip_kernel(float* __restrict__ c, int n) {
  int i = blockIdx.x * 256 + threadIdx.x;
  if (i < n) c[i] = 1.0f / fmaxf(c[i], 1.0f);
}

// ---------------- edge-parallel scatter-add (fp32 atomics, R2-validated) ----
// agg[dst[e]*D + d] += x[src[e]*D + d]; D = 1<<shift. XBF: x is bf16 else fp32.
template <bool XBF>
__global__ void edge_agg_kernel(const int* __restrict__ src, const int* __restrict__ dst,
                                const void* __restrict__ x, float* __restrict__ agg,
                                int E, int shift, int nsrc, int ndst) {
  long long i = (long long)blockIdx.x * 256 + threadIdx.x;
  if (i >= ((long long)E << shift)) return;
  int e = (int)(i >> shift);
  int d = (int)(i & ((1 << shift) - 1));
  int s = src[e];
  int t = dst[e];
  s = ((unsigned)s < (unsigned)nsrc) ? s : 0;
  if ((unsigned)t >= (unsigned)ndst) return;
  float v = XBF ? __bfloat162float(((const bf16*)x)[((long long)s << shift) + d])
                : ((const float*)x)[((long long)s << shift) + d];
  unsafeAtomicAdd(&agg[((long long)t << shift) + d], v);
}

// ---------------- weight transpose: Wt[c][k] = bf16(W[k][c]), W = [Wl;Wr] ----
__global__ void transpose_w_kernel(const float* __restrict__ Wl, const float* __restrict__ Wr,
                                   int Da, int K, int NCOL, ushort* __restrict__ Wt) {
  int i = blockIdx.x * 256 + threadIdx.x;
  if (i >= K * NCOL) return;
  int k = i / NCOL, c = i - k * NCOL;
  const float* srcp = (k < Da) ? (Wl + (long long)k * NCOL)
                               : (Wr + (long long)(k - Da) * NCOL);
  Wt[(long long)c * K + k] = f2bu(srcp[c]);
}

// ---------------- MFMA GEMM (no LDS) ----------------
// C[n x NCOL] = [A0 | A1] @ W + bias (fp32), optional relu.
// Wt pre-transposed bf16 [NCOL][K]. A segments dtype-templated:
//   0 = bf16, 1 = fp32, 2 = fp32 scaled by inv[row] (mean = agg * inv).
// MFMA 16x16x32_bf16 fragment maps (verified m89/m91):
//   A: lane(p,q) holds A[row=p][k=q*8..q*8+7]
//   B: lane(p,q) holds B[k=q*8..+7][col=p]  == Wt[col][k...]
//   C/D: col=p, row=q*4+reg
// Block = 256 thr = 4 waves; wave covers 32 rows (2 m-tiles), NCT col-tiles.
#define AT_BF16 0
#define AT_F32  1
#define AT_F32S 2
template <int KT, int NCT, int A0T, int A1T, bool OUTF32>
__global__ __launch_bounds__(256) void gemm_kernel(
    const void* __restrict__ A0, int lda0, int k0t,
    const void* __restrict__ A1, int lda1,
    const float* __restrict__ inv,
    const ushort* __restrict__ Wt, const float* __restrict__ bias,
    void* __restrict__ C, long long cbase, int ldc, int n, int relu) {
  constexpr int K = KT * 32;
  int tid = threadIdx.x;
  int wave = tid >> 6, lane = tid & 63;
  int p = lane & 15, q = lane >> 4;
  int row0 = blockIdx.x * 128 + wave * 32;

  int rr[2];
  float sc[2];
#pragma unroll
  for (int m = 0; m < 2; ++m) {
    rr[m] = min(row0 + m * 16 + p, n - 1);
    sc[m] = (A0T == AT_F32S) ? inv[rr[m]] : 1.0f;
  }

  float4v acc[2][NCT];
#pragma unroll
  for (int m = 0; m < 2; ++m)
#pragma unroll
    for (int t = 0; t < NCT; ++t) acc[m][t] = (float4v){0.f, 0.f, 0.f, 0.f};

  for (int kt = 0; kt < KT; ++kt) {
    bool seg0 = (kt < k0t);
    const void* abase = seg0 ? A0 : A1;
    int lda = seg0 ? lda0 : lda1;
    int kof = (seg0 ? kt : (kt - k0t)) * 32;
    int at = seg0 ? A0T : A1T;
    short8 af[2];
#pragma unroll
    for (int m = 0; m < 2; ++m) {
      long long base = (long long)rr[m] * lda + kof + q * 8;
      if (at == AT_BF16) {
        af[m] = *(const short8*)((const bf16*)abase + base);
      } else {
        const float* fb = (const float*)abase + base;
        float4 a = *(const float4*)fb;
        float4 b = *(const float4*)(fb + 4);
        float s = seg0 ? sc[m] : 1.0f;  // scale applies only to A0 (mean)
        short8 r;
        r[0] = (short)f2bu(a.x * s); r[1] = (short)f2bu(a.y * s);
        r[2] = (short)f2bu(a.z * s); r[3] = (short)f2bu(a.w * s);
        r[4] = (short)f2bu(b.x * s); r[5] = (short)f2bu(b.y * s);
        r[6] = (short)f2bu(b.z * s); r[7] = (short)f2bu(b.w * s);
        af[m] = r;
      }
    }
#pragma unroll
    for (int t = 0; t < NCT; ++t) {
      int c = t * 16 + p;
      short8 bfr = *(const short8*)(Wt + (long long)c * K + kt * 32 + q * 8);
      acc[0][t] = __builtin_amdgcn_mfma_f32_16x16x32_bf16(af[0], bfr, acc[0][t], 0, 0, 0);
      acc[1][t] = __builtin_amdgcn_mfma_f32_16x16x32_bf16(af[1], bfr, acc[1][t], 0, 0, 0);
    }
  }

#pragma unroll
  for (int t = 0; t < NCT; ++t) {
    int c = t * 16 + p;
    float bv = bias[c];
#pragma unroll
    for (int m = 0; m < 2; ++m) {
#pragma unroll
      for (int r = 0; r < 4; ++r) {
        int row = row0 + m * 16 + q * 4 + r;
        if (row < n) {
          float v = acc[m][t][r] + bv;
          if (relu) v = fmaxf(v, 0.f);
          long long idx = cbase + (long long)row * ldc + c;
          if (OUTF32) ((float*)C)[idx] = v;
          else        ((bf16*)C)[idx] = __float2bfloat16(v);
        }
      }
    }
  }
}

// ---------------- host ----------------
extern "C" void kernel_launch(void* const* d_in, const int* in_sizes, int n_in,
                              void* d_out, int out_size, void* d_ws,
                              size_t ws_size, hipStream_t stream) {
  const float* x_txn = (const float*)d_in[0];
  const float* x_cli = (const float*)d_in[1];
  const int* ct_src = (const int*)d_in[2];
  const int* ct_dst = (const int*)d_in[3];
  const int* tc_src = (const int*)d_in[4];
  const int* tc_dst = (const int*)d_in[5];
  const float* W1ctl = (const float*)d_in[6];
  const float* b1ct  = (const float*)d_in[7];
  const float* W1ctr = (const float*)d_in[8];
  const float* W1tcl = (const float*)d_in[9];
  const float* b1tc  = (const float*)d_in[10];
  const float* W1tcr = (const float*)d_in[11];
  const float* W2ctl = (const float*)d_in[12];
  const float* b2ct  = (const float*)d_in[13];
  const float* W2ctr = (const float*)d_in[14];
  const float* W2tcl = (const float*)d_in[15];
  const float* b2tc  = (const float*)d_in[16];
  const float* W2tcr = (const float*)d_in[17];
  const float* Wd1   = (const float*)d_in[18];
  const float* bd1   = (const float*)d_in[19];
  const float* Wd2   = (const float*)d_in[20];
  const float* bd2   = (const float*)d_in[21];

  const int E = in_sizes[2];  // 600000
  const int NT = 100000, NC = 20000;

  // ---- workspace carve: total ~82.6 MB (< 92.64 MB proven bound) ----
  size_t o = 0;
  auto carve = [&](size_t bytes) {
    void* p = (char*)d_ws + o;
    o = (o + bytes + 255) & ~(size_t)255;
    return p;
  };
  float* inv_ct = (float*)carve((size_t)NT * 4);
  float* inv_tc = (float*)carve((size_t)NC * 4);
  ushort* Wt1 = (ushort*)carve((size_t)96 * 128 * 2);
  ushort* Wt2 = (ushort*)carve((size_t)96 * 128 * 2);
  ushort* Wt3 = (ushort*)carve((size_t)256 * 128 * 2);
  ushort* Wt4 = (ushort*)carve((size_t)256 * 128 * 2);
  ushort* Wt5 = (ushort*)carve((size_t)128 * 64 * 2);
  ushort* Wt6 = (ushort*)carve((size_t)64 * 64 * 2);
  bf16* h_txn = (bf16*)carve((size_t)NT * 128 * 2);              // 25.6 MB
  bf16* h_cli = (bf16*)carve((size_t)NC * 128 * 2);              // 5.12 MB
  float* aggb = (float*)carve((size_t)NT * 128 * 4);             // 51.2 MB
  (void)ws_size;
  // overlays in aggb:
  float* agg1_ct = aggb;                   // NT*32  (layer 1, concurrent)
  float* agg1_tc = aggb + (size_t)NT * 32; // NC*64
  bf16*  dec_t   = (bf16*)aggb;            // NT*64 bf16 (decoder, aggb dead)

  const int tb = 256;
  const int nbE = (E + tb - 1) / tb;

  // weight transposes (tiny)
  transpose_w_kernel<<<(96 * 128 + 255) / 256, tb, 0, stream>>>(W1ctl, W1ctr, 32, 96, 128, Wt1);
  transpose_w_kernel<<<(96 * 128 + 255) / 256, tb, 0, stream>>>(W1tcl, W1tcr, 64, 96, 128, Wt2);
  transpose_w_kernel<<<(256 * 128 + 255) / 256, tb, 0, stream>>>(W2ctl, W2ctr, 128, 256, 128, Wt3);
  transpose_w_kernel<<<(256 * 128 + 255) / 256, tb, 0, stream>>>(W2tcl, W2tcr, 128, 256, 128, Wt4);
  transpose_w_kernel<<<(128 * 64 + 255) / 256, tb, 0, stream>>>(Wd1, Wd1, 128, 128, 64, Wt5);
  transpose_w_kernel<<<(64 * 64 + 255) / 256, tb, 0, stream>>>(Wd2, Wd2, 64, 64, 64, Wt6);

  // degree counts -> in-place reciprocal
  hipMemsetAsync(inv_ct, 0, (size_t)NT * 4, stream);
  hipMemsetAsync(inv_tc, 0, (size_t)NC * 4, stream);
  count_deg_kernel<<<nbE, tb, 0, stream>>>(ct_dst, inv_ct, E, NT);
  count_deg_kernel<<<nbE, tb, 0, stream>>>(tc_dst, inv_tc, E, NC);
  recip_kernel<<<(NT + 255) / 256, tb, 0, stream>>>(inv_ct, NT);
  recip_kernel<<<(NC + 255) / 256, tb, 0, stream>>>(inv_tc, NC);

  const int gb_t = (NT + 127) / 128;  // 782
  const int gb_c = (NC + 127) / 128;  // 157

  // ---- layer 1 aggregation (fp32 x, atomics) ----
  hipMemsetAsync(aggb, 0, (size_t)(NT * 32 + NC * 64) * 4, stream);
  {
    long long tot = (long long)E << 5;
    edge_agg_kernel<false><<<(int)((tot + tb - 1) / tb), tb, 0, stream>>>(
        ct_src, ct_dst, x_cli, agg1_ct, E, 5, NC, NT);
    tot = (long long)E << 6;
    edge_agg_kernel<false><<<(int)((tot + tb - 1) / tb), tb, 0, stream>>>(
        tc_src, tc_dst, x_txn, agg1_tc, E, 6, NT, NC);
  }

  // ---- layer 1 linears: h = relu([mean|x] @ W + b), K=96, bf16 out ----
  gemm_kernel<3, 8, AT_F32S, AT_F32, false><<<gb_t, tb, 0, stream>>>(
      agg1_ct, 32, 1, x_txn, 64, inv_ct, Wt1, b1ct, h_txn, 0, 128, NT, 1);
  gemm_kernel<3, 8, AT_F32S, AT_F32, false><<<gb_c, tb, 0, stream>>>(
      agg1_tc, 64, 2, x_cli, 32, inv_tc, Wt2, b1tc, h_cli, 0, 128, NC, 1);

  float* out = (float*)d_out;
  const long long ztxn_base = (long long)NT * 64;
  const long long zcli_base = ztxn_base + (long long)NT * 128;

  // ---- layer 2, txn side (aggb reused sequentially) ----
  hipMemsetAsync(aggb, 0, (size_t)NT * 128 * 4, stream);
  {
    long long tot = (long long)E << 7;
    edge_agg_kernel<true><<<(int)((tot + tb - 1) / tb), tb, 0, stream>>>(
        ct_src, ct_dst, h_cli, aggb, E, 7, NC, NT);
  }
  gemm_kernel<8, 8, AT_F32S, AT_BF16, true><<<gb_t, tb, 0, stream>>>(
      aggb, 128, 4, h_txn, 128, inv_ct, Wt3, b2ct, out, ztxn_base, 128, NT, 0);

  // ---- layer 2, client side ----
  hipMemsetAsync(aggb, 0, (size_t)NC * 128 * 4, stream);
  {
    long long tot = (long long)E << 7;
    edge_agg_kernel<true><<<(int)((tot + tb - 1) / tb), tb, 0, stream>>>(
        tc_src, tc_dst, h_txn, aggb, E, 7, NT, NC);
  }
  gemm_kernel<8, 8, AT_F32S, AT_BF16, true><<<gb_c, tb, 0, stream>>>(
      aggb, 128, 4, h_cli, 128, inv_tc, Wt4, b2tc, out, zcli_base, 128, NC, 0);

  // ---- decoder: recon = relu(z @ Wd1 + b) @ Wd2 + b (z fp32 in d_out) ----
  gemm_kernel<4, 4, AT_F32, AT_F32, false><<<gb_t, tb, 0, stream>>>(
      out + ztxn_base, 128, 4, out + ztxn_base, 128, nullptr, Wt5, bd1,
      dec_t, 0, 64, NT, 1);
  gemm_kernel<2, 4, AT_BF16, AT_BF16, true><<<gb_t, tb, 0, stream>>>(
      dec_t, 64, 2, dec_t, 64, nullptr, Wt6, bd2, out, 0, 64, NT, 0);
}

// Round 7
// 639.774 us; speedup vs baseline: 3.0111x; 1.8307x over previous
//
#include <hip/hip_runtime.h>
#include <hip/hip_bf16.h>

typedef __hip_bfloat16 bf16;
typedef unsigned int uint;
typedef unsigned short ushort;
typedef __attribute__((ext_vector_type(8))) short short8;   // 8 bf16 = 4 VGPR
typedef __attribute__((ext_vector_type(4))) float float4v;  // MFMA acc

__device__ __forceinline__ float lo2f(uint v) { return __uint_as_float(v << 16); }
__device__ __forceinline__ float hi2f(uint v) { return __uint_as_float(v & 0xffff0000u); }
__device__ __forceinline__ ushort f2bu(float v) {
  union { bf16 h; ushort u; } x;
  x.h = __float2bfloat16(v);
  return x.u;
}
__device__ __forceinline__ uint packbf2(float a, float b) {
  return (uint)f2bu(a) | ((uint)f2bu(b) << 16);
}

// ======================= CSR build (int-only, dtype-independent) =============
__global__ void count_kernel(const int* __restrict__ dst, int* __restrict__ deg,
                             int E, int n) {
  int e = blockIdx.x * 256 + threadIdx.x;
  if (e < E) {
    int d = dst[e];
    if ((unsigned)d < (unsigned)n) atomicAdd(&deg[d], 1);
  }
}

__global__ void sum_block_kernel(const int* __restrict__ v, int* __restrict__ bsum, int n) {
  __shared__ int s[256];
  int t = threadIdx.x;
  int i = blockIdx.x * 256 + t;
  s[t] = (i < n) ? v[i] : 0;
  __syncthreads();
  for (int o = 128; o > 0; o >>= 1) {
    if (t < o) s[t] += s[t + o];
    __syncthreads();
  }
  if (t == 0) bsum[blockIdx.x] = s[0];
}

__global__ void scan_bsum_kernel(int* __restrict__ bsum, int nb) {
  __shared__ int s[1024];
  int t = threadIdx.x;
  int v = (t < nb) ? bsum[t] : 0;
  s[t] = v;
  __syncthreads();
  for (int o = 1; o < 1024; o <<= 1) {
    int x = (t >= o) ? s[t - o] : 0;
    __syncthreads();
    s[t] += x;
    __syncthreads();
  }
  if (t < nb) bsum[t] = s[t] - v;  // exclusive block offsets
}

__global__ void scan_final_kernel(const int* __restrict__ deg, const int* __restrict__ bsum,
                                  int* __restrict__ off, int* __restrict__ cur, int n) {
  __shared__ int s[256];
  int t = threadIdx.x;
  int i = blockIdx.x * 256 + t;
  int v = (i < n) ? deg[i] : 0;
  s[t] = v;
  __syncthreads();
  for (int o = 1; o < 256; o <<= 1) {
    int x = (t >= o) ? s[t - o] : 0;
    __syncthreads();
    s[t] += x;
    __syncthreads();
  }
  int excl = bsum[blockIdx.x] + s[t] - v;
  if (i < n) { off[i] = excl; cur[i] = excl; }
  if (i == n - 1) off[n] = excl + v;
}

__global__ void scatter_kernel(const int* __restrict__ src, const int* __restrict__ dst,
                               int* __restrict__ cur, int* __restrict__ csr, int E, int n) {
  int e = blockIdx.x * 256 + threadIdx.x;
  if (e < E) {
    int d = dst[e];
    if ((unsigned)d < (unsigned)n) {
      int p = atomicAdd(&cur[d], 1);
      if ((unsigned)p < (unsigned)E) csr[p] = src[e];
    }
  }
}

// ======================= pull aggregation (mean, bf16 out) ===================
// One wave per 64/(D/2) nodes-slot; LPR = D/2 lanes cover a row (8B fp32 or
// 4B bf16x2 per lane); PAR = 64/LPR edges processed in parallel, combined by
// shuffle. Mean (1/deg folded) written once as packed bf16 — zero atomics.
template <int D, bool XBF>
__global__ __launch_bounds__(256) void pull_mean_kernel(
    const int* __restrict__ off, const int* __restrict__ csr,
    const void* __restrict__ x, bf16* __restrict__ mean, int n, int nsrc) {
  constexpr int LPR = D / 2;
  constexpr int PAR = 64 / LPR;
  int node = blockIdx.x * 4 + (threadIdx.x >> 6);
  if (node >= n) return;  // wave-uniform
  int lane = threadIdx.x & 63;
  int h = lane / LPR, col = lane % LPR;
  int beg = off[node], deg = off[node + 1] - beg;
  float inv = 1.0f / fmaxf((float)deg, 1.0f);
  float ax = 0.f, ay = 0.f;
  for (int i = h; i < deg; i += PAR) {
    int s = csr[beg + i];
    s = ((unsigned)s < (unsigned)nsrc) ? s : 0;
    if (XBF) {
      uint v = ((const uint*)x)[(long long)s * LPR + col];
      ax += lo2f(v); ay += hi2f(v);
    } else {
      float2 v = ((const float2*)x)[(long long)s * LPR + col];
      ax += v.x; ay += v.y;
    }
  }
#pragma unroll
  for (int m = LPR; m < 64; m <<= 1) {
    ax += __shfl_xor(ax, m);
    ay += __shfl_xor(ay, m);
  }
  if (h == 0)
    ((uint*)mean)[(long long)node * LPR + col] = packbf2(ax * inv, ay * inv);
}

// ======================= weight transpose ====================================
// Wt[c][k] = bf16(W[k][c]), W = [Wl (Da rows); Wr (K-Da rows)], row-major NCOL.
__global__ void transpose_w_kernel(const float* __restrict__ Wl, const float* __restrict__ Wr,
                                   int Da, int K, int NCOL, ushort* __restrict__ Wt) {
  int i = blockIdx.x * 256 + threadIdx.x;
  if (i >= K * NCOL) return;
  int k = i / NCOL, c = i - k * NCOL;
  const float* srcp = (k < Da) ? (Wl + (long long)k * NCOL)
                               : (Wr + (long long)(k - Da) * NCOL);
  Wt[(long long)c * K + k] = f2bu(srcp[c]);
}

// ======================= MFMA GEMM (no LDS) — R6-validated ===================
// C[n x NCOL] = [A0 | A1] @ W + bias (fp32), optional relu.
// Wt pre-transposed bf16 [NCOL][K]. A segments dtype-templated.
// Fragment maps (verified m89/m91): A: lane(p,q)->A[p][q*8..+7];
// B: lane(p,q)->Wt[col=p][k=q*8..+7]; C/D: col=p, row=q*4+reg.
#define AT_BF16 0
#define AT_F32  1
template <int KT, int NCT, int A0T, int A1T, bool OUTF32>
__global__ __launch_bounds__(256) void gemm_kernel(
    const void* __restrict__ A0, int lda0, int k0t,
    const void* __restrict__ A1, int lda1,
    const ushort* __restrict__ Wt, const float* __restrict__ bias,
    void* __restrict__ C, long long cbase, int ldc, int n, int relu) {
  constexpr int K = KT * 32;
  int tid = threadIdx.x;
  int wave = tid >> 6, lane = tid & 63;
  int p = lane & 15, q = lane >> 4;
  int row0 = blockIdx.x * 128 + wave * 32;

  int rr[2];
#pragma unroll
  for (int m = 0; m < 2; ++m) rr[m] = min(row0 + m * 16 + p, n - 1);

  float4v acc[2][NCT];
#pragma unroll
  for (int m = 0; m < 2; ++m)
#pragma unroll
    for (int t = 0; t < NCT; ++t) acc[m][t] = (float4v){0.f, 0.f, 0.f, 0.f};

  for (int kt = 0; kt < KT; ++kt) {
    bool seg0 = (kt < k0t);
    const void* abase = seg0 ? A0 : A1;
    int lda = seg0 ? lda0 : lda1;
    int kof = (seg0 ? kt : (kt - k0t)) * 32;
    int at = seg0 ? A0T : A1T;
    short8 af[2];
#pragma unroll
    for (int m = 0; m < 2; ++m) {
      long long base = (long long)rr[m] * lda + kof + q * 8;
      if (at == AT_BF16) {
        af[m] = *(const short8*)((const bf16*)abase + base);
      } else {
        const float* fb = (const float*)abase + base;
        float4 a = *(const float4*)fb;
        float4 b = *(const float4*)(fb + 4);
        short8 r;
        r[0] = (short)f2bu(a.x); r[1] = (short)f2bu(a.y);
        r[2] = (short)f2bu(a.z); r[3] = (short)f2bu(a.w);
        r[4] = (short)f2bu(b.x); r[5] = (short)f2bu(b.y);
        r[6] = (short)f2bu(b.z); r[7] = (short)f2bu(b.w);
        af[m] = r;
      }
    }
#pragma unroll
    for (int t = 0; t < NCT; ++t) {
      int c = t * 16 + p;
      short8 bfr = *(const short8*)(Wt + (long long)c * K + kt * 32 + q * 8);
      acc[0][t] = __builtin_amdgcn_mfma_f32_16x16x32_bf16(af[0], bfr, acc[0][t], 0, 0, 0);
      acc[1][t] = __builtin_amdgcn_mfma_f32_16x16x32_bf16(af[1], bfr, acc[1][t], 0, 0, 0);
    }
  }

#pragma unroll
  for (int t = 0; t < NCT; ++t) {
    int c = t * 16 + p;
    float bv = bias[c];
#pragma unroll
    for (int m = 0; m < 2; ++m) {
#pragma unroll
      for (int r = 0; r < 4; ++r) {
        int row = row0 + m * 16 + q * 4 + r;
        if (row < n) {
          float v = acc[m][t][r] + bv;
          if (relu) v = fmaxf(v, 0.f);
          long long idx = cbase + (long long)row * ldc + c;
          if (OUTF32) ((float*)C)[idx] = v;
          else        ((bf16*)C)[idx] = __float2bfloat16(v);
        }
      }
    }
  }
}

// ======================= host ================================================
extern "C" void kernel_launch(void* const* d_in, const int* in_sizes, int n_in,
                              void* d_out, int out_size, void* d_ws,
                              size_t ws_size, hipStream_t stream) {
  const float* x_txn = (const float*)d_in[0];
  const float* x_cli = (const float*)d_in[1];
  const int* ct_src = (const int*)d_in[2];
  const int* ct_dst = (const int*)d_in[3];
  const int* tc_src = (const int*)d_in[4];
  const int* tc_dst = (const int*)d_in[5];
  const float* W1ctl = (const float*)d_in[6];
  const float* b1ct  = (const float*)d_in[7];
  const float* W1ctr = (const float*)d_in[8];
  const float* W1tcl = (const float*)d_in[9];
  const float* b1tc  = (const float*)d_in[10];
  const float* W1tcr = (const float*)d_in[11];
  const float* W2ctl = (const float*)d_in[12];
  const float* b2ct  = (const float*)d_in[13];
  const float* W2ctr = (const float*)d_in[14];
  const float* W2tcl = (const float*)d_in[15];
  const float* b2tc  = (const float*)d_in[16];
  const float* W2tcr = (const float*)d_in[17];
  const float* Wd1   = (const float*)d_in[18];
  const float* bd1   = (const float*)d_in[19];
  const float* Wd2   = (const float*)d_in[20];
  const float* bd2   = (const float*)d_in[21];

  const int E = in_sizes[2];  // 600000
  const int NT = 100000, NC = 20000;

  // ---- workspace carve: ~77 MB (< 92.64 MB proven bound) ----
  size_t o = 0;
  auto carve = [&](size_t bytes) {
    void* p = (char*)d_ws + o;
    o = (o + bytes + 255) & ~(size_t)255;
    return p;
  };
  int* deg_ct  = (int*)carve((size_t)NT * 4);
  int* deg_tc  = (int*)carve((size_t)NC * 4);
  size_t zero_bytes = o;  // deg regions only
  int* bsum_ct = (int*)carve(2048);
  int* bsum_tc = (int*)carve(2048);
  int* off_ct = (int*)carve((size_t)(NT + 1) * 4);
  int* off_tc = (int*)carve((size_t)(NC + 1) * 4);
  int* cur_ct = (int*)carve((size_t)NT * 4);
  int* cur_tc = (int*)carve((size_t)NC * 4);
  int* csr_ct = (int*)carve((size_t)E * 4);
  int* csr_tc = (int*)carve((size_t)E * 4);
  ushort* Wt1 = (ushort*)carve((size_t)96 * 128 * 2);
  ushort* Wt2 = (ushort*)carve((size_t)96 * 128 * 2);
  ushort* Wt3 = (ushort*)carve((size_t)256 * 128 * 2);
  ushort* Wt4 = (ushort*)carve((size_t)256 * 128 * 2);
  ushort* Wt5 = (ushort*)carve((size_t)128 * 64 * 2);
  ushort* Wt6 = (ushort*)carve((size_t)64 * 64 * 2);
  bf16* mean1_ct = (bf16*)carve((size_t)NT * 32 * 2);
  bf16* mean1_tc = (bf16*)carve((size_t)NC * 64 * 2);
  bf16* h_txn    = (bf16*)carve((size_t)NT * 128 * 2);
  bf16* h_cli    = (bf16*)carve((size_t)NC * 128 * 2);
  bf16* mean2_ct = (bf16*)carve((size_t)NT * 128 * 2);   // also aliased by dec_t
  bf16* mean2_tc = (bf16*)carve((size_t)NC * 128 * 2);
  bf16* dec_t = mean2_ct;  // dead by decoder time (12.8 MB <= 25.6 MB)
  (void)ws_size;

  hipMemsetAsync(d_ws, 0, zero_bytes, stream);

  const int tb = 256;
  const int nbE = (E + 255) / 256;
  const int nb_ct = (NT + 255) / 256;  // 391
  const int nb_tc = (NC + 255) / 256;  // 79

  // weight transposes (tiny)
  transpose_w_kernel<<<(96 * 128 + 255) / 256, tb, 0, stream>>>(W1ctl, W1ctr, 32, 96, 128, Wt1);
  transpose_w_kernel<<<(96 * 128 + 255) / 256, tb, 0, stream>>>(W1tcl, W1tcr, 64, 96, 128, Wt2);
  transpose_w_kernel<<<(256 * 128 + 255) / 256, tb, 0, stream>>>(W2ctl, W2ctr, 128, 256, 128, Wt3);
  transpose_w_kernel<<<(256 * 128 + 255) / 256, tb, 0, stream>>>(W2tcl, W2tcr, 128, 256, 128, Wt4);
  transpose_w_kernel<<<(128 * 64 + 255) / 256, tb, 0, stream>>>(Wd1, Wd1, 128, 128, 64, Wt5);
  transpose_w_kernel<<<(64 * 64 + 255) / 256, tb, 0, stream>>>(Wd2, Wd2, 64, 64, 64, Wt6);

  // CSR build (reused by both layers)
  count_kernel<<<nbE, tb, 0, stream>>>(ct_dst, deg_ct, E, NT);
  count_kernel<<<nbE, tb, 0, stream>>>(tc_dst, deg_tc, E, NC);
  sum_block_kernel<<<nb_ct, tb, 0, stream>>>(deg_ct, bsum_ct, NT);
  sum_block_kernel<<<nb_tc, tb, 0, stream>>>(deg_tc, bsum_tc, NC);
  scan_bsum_kernel<<<1, 1024, 0, stream>>>(bsum_ct, nb_ct);
  scan_bsum_kernel<<<1, 1024, 0, stream>>>(bsum_tc, nb_tc);
  scan_final_kernel<<<nb_ct, tb, 0, stream>>>(deg_ct, bsum_ct, off_ct, cur_ct, NT);
  scan_final_kernel<<<nb_tc, tb, 0, stream>>>(deg_tc, bsum_tc, off_tc, cur_tc, NC);
  scatter_kernel<<<nbE, tb, 0, stream>>>(ct_src, ct_dst, cur_ct, csr_ct, E, NT);
  scatter_kernel<<<nbE, tb, 0, stream>>>(tc_src, tc_dst, cur_tc, csr_tc, E, NC);

  const int gb_t = (NT + 127) / 128;  // 782
  const int gb_c = (NC + 127) / 128;  // 157

  // layer 1: pull means (fp32 inputs) then fused linears
  pull_mean_kernel<32, false><<<(NT + 3) / 4, tb, 0, stream>>>(
      off_ct, csr_ct, x_cli, mean1_ct, NT, NC);
  pull_mean_kernel<64, false><<<(NC + 3) / 4, tb, 0, stream>>>(
      off_tc, csr_tc, x_txn, mean1_tc, NC, NT);

  gemm_kernel<3, 8, AT_BF16, AT_F32, false><<<gb_t, tb, 0, stream>>>(
      mean1_ct, 32, 1, x_txn, 64, Wt1, b1ct, h_txn, 0, 128, NT, 1);
  gemm_kernel<3, 8, AT_BF16, AT_F32, false><<<gb_c, tb, 0, stream>>>(
      mean1_tc, 64, 2, x_cli, 32, Wt2, b1tc, h_cli, 0, 128, NC, 1);

  // layer 2: pull means (bf16 h) then fused linears
  pull_mean_kernel<128, true><<<(NT + 3) / 4, tb, 0, stream>>>(
      off_ct, csr_ct, h_cli, mean2_ct, NT, NC);
  pull_mean_kernel<128, true><<<(NC + 3) / 4, tb, 0, stream>>>(
      off_tc, csr_tc, h_txn, mean2_tc, NC, NT);

  float* out = (float*)d_out;
  const long long ztxn_base = (long long)NT * 64;
  const long long zcli_base = ztxn_base + (long long)NT * 128;

  gemm_kernel<8, 8, AT_BF16, AT_BF16, true><<<gb_t, tb, 0, stream>>>(
      mean2_ct, 128, 4, h_txn, 128, Wt3, b2ct, out, ztxn_base, 128, NT, 0);
  gemm_kernel<8, 8, AT_BF16, AT_BF16, true><<<gb_c, tb, 0, stream>>>(
      mean2_tc, 128, 4, h_cli, 128, Wt4, b2tc, out, zcli_base, 128, NC, 0);

  // decoder: recon = relu(z @ Wd1 + b) @ Wd2 + b  (z fp32 in d_out)
  gemm_kernel<4, 4, AT_F32, AT_F32, false><<<gb_t, tb, 0, stream>>>(
      out + ztxn_base, 128, 4, out + ztxn_base, 128, Wt5, bd1, dec_t, 0, 64, NT, 1);
  gemm_kernel<2, 4, AT_BF16, AT_BF16, true><<<gb_t, tb, 0, stream>>>(
      dec_t, 64, 2, dec_t, 64, Wt6, bd2, out, 0, 64, NT, 0);
}

// Round 8
// 574.701 us; speedup vs baseline: 3.3520x; 1.1132x over previous
//
#include <hip/hip_runtime.h>
#include <hip/hip_bf16.h>

typedef __hip_bfloat16 bf16;
typedef unsigned int uint;
typedef unsigned short ushort;
typedef __attribute__((ext_vector_type(8))) short short8;   // 8 bf16 = 4 VGPR
typedef __attribute__((ext_vector_type(4))) float float4v;  // MFMA acc

__device__ __forceinline__ float lo2f(uint v) { return __uint_as_float(v << 16); }
__device__ __forceinline__ float hi2f(uint v) { return __uint_as_float(v & 0xffff0000u); }
__device__ __forceinline__ ushort f2bu(float v) {
  union { bf16 h; ushort u; } x;
  x.h = __float2bfloat16(v);
  return x.u;
}
__device__ __forceinline__ uint packbf2(float a, float b) {
  return (uint)f2bu(a) | ((uint)f2bu(b) << 16);
}

// ======================= fused weight transpose (6 jobs, 1 launch) ===========
struct TJob { const float* wl; const float* wr; ushort* dst; int da, k, ncol, boff; };
struct TJobs { TJob j[6]; };

__global__ void transpose6_kernel(TJobs js) {
  int b = blockIdx.x;
  int jj = 0;
#pragma unroll
  for (int t = 1; t < 6; ++t)
    if (b >= js.j[t].boff) jj = t;
  const TJob J = js.j[jj];
  int i = (b - J.boff) * 256 + threadIdx.x;
  if (i >= J.k * J.ncol) return;
  int k = i / J.ncol, c = i - k * J.ncol;
  const float* srcp = (k < J.da) ? (J.wl + (long long)k * J.ncol)
                                 : (J.wr + (long long)(k - J.da) * J.ncol);
  J.dst[(long long)c * J.k + k] = f2bu(srcp[c]);
}

// ======================= CSR build (fused pairs) =============================
__global__ void count2_kernel(const int* __restrict__ dstA, int* __restrict__ degA, int nA,
                              const int* __restrict__ dstB, int* __restrict__ degB, int nB,
                              int E, int nbA) {
  int b = blockIdx.x;
  const int* dst; int* deg; int n;
  if (b < nbA) { dst = dstA; deg = degA; n = nA; }
  else         { b -= nbA; dst = dstB; deg = degB; n = nB; }
  int e = b * 256 + threadIdx.x;
  if (e < E) {
    int d = dst[e];
    if ((unsigned)d < (unsigned)n) atomicAdd(&deg[d], 1);
  }
}

__global__ void sum_block2_kernel(const int* __restrict__ vA, int nA, int nbA, int* __restrict__ bsA,
                                  const int* __restrict__ vB, int nB, int* __restrict__ bsB) {
  __shared__ int s[256];
  int b = blockIdx.x;
  const int* v; int n; int* bs;
  if (b < nbA) { v = vA; n = nA; bs = bsA; }
  else         { b -= nbA; v = vB; n = nB; bs = bsB; }
  int t = threadIdx.x;
  int i = b * 256 + t;
  s[t] = (i < n) ? v[i] : 0;
  __syncthreads();
  for (int o = 128; o > 0; o >>= 1) {
    if (t < o) s[t] += s[t + o];
    __syncthreads();
  }
  if (t == 0) bs[b] = s[0];
}

__global__ void scan_bsum2_kernel(int* __restrict__ bsA, int nbA,
                                  int* __restrict__ bsB, int nbB) {
  __shared__ int s[1024];
  int* bs = (blockIdx.x == 0) ? bsA : bsB;
  int nb  = (blockIdx.x == 0) ? nbA : nbB;
  int t = threadIdx.x;
  int v = (t < nb) ? bs[t] : 0;
  s[t] = v;
  __syncthreads();
  for (int o = 1; o < 1024; o <<= 1) {
    int x = (t >= o) ? s[t - o] : 0;
    __syncthreads();
    s[t] += x;
    __syncthreads();
  }
  if (t < nb) bs[t] = s[t] - v;  // exclusive block offsets
}

__global__ void scan_final2_kernel(const int* __restrict__ degA, const int* __restrict__ bsA,
                                   int* __restrict__ offA, int* __restrict__ curA, int nA, int nbA,
                                   const int* __restrict__ degB, const int* __restrict__ bsB,
                                   int* __restrict__ offB, int* __restrict__ curB, int nB) {
  __shared__ int s[256];
  int b = blockIdx.x;
  const int *deg, *bsum; int *off, *cur; int n;
  if (b < nbA) { deg = degA; bsum = bsA; off = offA; cur = curA; n = nA; }
  else         { b -= nbA; deg = degB; bsum = bsB; off = offB; cur = curB; n = nB; }
  int t = threadIdx.x;
  int i = b * 256 + t;
  int v = (i < n) ? deg[i] : 0;
  s[t] = v;
  __syncthreads();
  for (int o = 1; o < 256; o <<= 1) {
    int x = (t >= o) ? s[t - o] : 0;
    __syncthreads();
    s[t] += x;
    __syncthreads();
  }
  int excl = bsum[b] + s[t] - v;
  if (i < n) { off[i] = excl; cur[i] = excl; }
  if (i == n - 1) off[n] = excl + v;
}

__global__ void scatter2_kernel(const int* __restrict__ srcA, const int* __restrict__ dstA,
                                int* __restrict__ curA, int* __restrict__ csrA, int nA,
                                const int* __restrict__ srcB, const int* __restrict__ dstB,
                                int* __restrict__ curB, int* __restrict__ csrB, int nB,
                                int E, int nbA) {
  int b = blockIdx.x;
  const int *src, *dst; int *cur, *csr; int n;
  if (b < nbA) { src = srcA; dst = dstA; cur = curA; csr = csrA; n = nA; }
  else         { b -= nbA; src = srcB; dst = dstB; cur = curB; csr = csrB; n = nB; }
  int e = b * 256 + threadIdx.x;
  if (e < E) {
    int d = dst[e];
    if ((unsigned)d < (unsigned)n) {
      int p = atomicAdd(&cur[d], 1);
      if ((unsigned)p < (unsigned)E) csr[p] = src[e];
    }
  }
}

// ======================= pull aggregation (mean, bf16 out) ===================
// One wave per node; LPR lanes cover a row; PAR = 64/LPR edges in flight.
// fp32 input: float4/lane (4 elems). bf16 input: uint2/lane (4 elems).
// Mean (1/deg folded) written once as packed bf16 — zero atomics.
template <int D, bool XBF>
__global__ __launch_bounds__(256) void pull_mean_kernel(
    const int* __restrict__ off, const int* __restrict__ csr,
    const void* __restrict__ x, bf16* __restrict__ mean, int n, int nsrc) {
  constexpr int LPR = D / 4;          // lanes per row (4 elems per lane)
  constexpr int PAR = 64 / LPR;       // edges in parallel
  int node = blockIdx.x * 4 + (threadIdx.x >> 6);
  if (node >= n) return;  // wave-uniform
  int lane = threadIdx.x & 63;
  int h = lane / LPR, col = lane % LPR;
  int beg = off[node], deg = off[node + 1] - beg;
  float inv = 1.0f / fmaxf((float)deg, 1.0f);
  float a0 = 0.f, a1 = 0.f, a2 = 0.f, a3 = 0.f;
  for (int i = h; i < deg; i += PAR) {
    int s = csr[beg + i];
    s = ((unsigned)s < (unsigned)nsrc) ? s : 0;
    if (XBF) {
      uint2 v = ((const uint2*)x)[(long long)s * LPR + col];
      a0 += lo2f(v.x); a1 += hi2f(v.x); a2 += lo2f(v.y); a3 += hi2f(v.y);
    } else {
      float4 v = ((const float4*)x)[(long long)s * LPR + col];
      a0 += v.x; a1 += v.y; a2 += v.z; a3 += v.w;
    }
  }
#pragma unroll
  for (int m = LPR; m < 64; m <<= 1) {
    a0 += __shfl_xor(a0, m); a1 += __shfl_xor(a1, m);
    a2 += __shfl_xor(a2, m); a3 += __shfl_xor(a3, m);
  }
  if (h == 0) {
    uint2 o2;
    o2.x = packbf2(a0 * inv, a1 * inv);
    o2.y = packbf2(a2 * inv, a3 * inv);
    ((uint2*)mean)[(long long)node * LPR + col] = o2;
  }
}

// ======================= MFMA GEMM (no LDS, branch-free unrolled K) ==========
// C[n x NCOL] = [A0 | A1] @ W + bias (fp32), optional relu.
// Wt pre-transposed bf16 [NCOL][K]. Segment split K0T is COMPILE-TIME so the
// fully-unrolled kt loop is branch-free -> compiler software-pipelines loads.
// Block = 256 thr = 4 waves; each wave: 1 m-tile (16 rows), NCT col-tiles.
// Fragment maps (verified m89/m91): A: lane(p,q)->A[p][q*8..+7];
// B: lane(p,q)->Wt[col=p][k=q*8..+7]; C/D: col=p, row=q*4+reg.
#define AT_BF16 0
#define AT_F32  1
template <int KT, int NCT, int K0T, int A0T, int A1T, bool OUTF32>
__global__ __launch_bounds__(256) void gemm_kernel(
    const void* __restrict__ A0, int lda0,
    const void* __restrict__ A1, int lda1,
    const ushort* __restrict__ Wt, const float* __restrict__ bias,
    void* __restrict__ C, long long cbase, int ldc, int n, int relu) {
  constexpr int K = KT * 32;
  int tid = threadIdx.x;
  int wave = tid >> 6, lane = tid & 63;
  int p = lane & 15, q = lane >> 4;
  int rowbase = blockIdx.x * 64 + wave * 16;
  int rcl = min(rowbase + p, n - 1);  // A-load row for this lane

  float4v acc[NCT];
#pragma unroll
  for (int t = 0; t < NCT; ++t) acc[t] = (float4v){0.f, 0.f, 0.f, 0.f};

#pragma unroll
  for (int kt = 0; kt < KT; ++kt) {
    const bool seg0 = (kt < K0T);                      // compile-time after unroll
    const void* ab = seg0 ? A0 : A1;
    const int lda = seg0 ? lda0 : lda1;
    const int kof = (seg0 ? kt : (kt - K0T)) * 32;
    const int at = seg0 ? A0T : A1T;
    short8 af;
    {
      long long base = (long long)rcl * lda + kof + q * 8;
      if (at == AT_BF16) {
        af = *(const short8*)((const bf16*)ab + base);
      } else {
        const float* fb = (const float*)ab + base;
        float4 a = *(const float4*)fb;
        float4 b = *(const float4*)(fb + 4);
        short8 r;
        r[0] = (short)f2bu(a.x); r[1] = (short)f2bu(a.y);
        r[2] = (short)f2bu(a.z); r[3] = (short)f2bu(a.w);
        r[4] = (short)f2bu(b.x); r[5] = (short)f2bu(b.y);
        r[6] = (short)f2bu(b.z); r[7] = (short)f2bu(b.w);
        af = r;
      }
    }
#pragma unroll
    for (int t = 0; t < NCT; ++t) {
      int c = t * 16 + p;
      short8 bfr = *(const short8*)(Wt + (long long)c * K + kt * 32 + q * 8);
      acc[t] = __builtin_amdgcn_mfma_f32_16x16x32_bf16(af, bfr, acc[t], 0, 0, 0);
    }
  }

#pragma unroll
  for (int t = 0; t < NCT; ++t) {
    int c = t * 16 + p;
    float bv = bias[c];
#pragma unroll
    for (int r = 0; r < 4; ++r) {
      int row = rowbase + q * 4 + r;
      if (row < n) {
        float v = acc[t][r] + bv;
        if (relu) v = fmaxf(v, 0.f);
        long long idx = cbase + (long long)row * ldc + c;
        if (OUTF32) ((float*)C)[idx] = v;
        else        ((bf16*)C)[idx] = __float2bfloat16(v);
      }
    }
  }
}

// ======================= host ================================================
extern "C" void kernel_launch(void* const* d_in, const int* in_sizes, int n_in,
                              void* d_out, int out_size, void* d_ws,
                              size_t ws_size, hipStream_t stream) {
  const float* x_txn = (const float*)d_in[0];
  const float* x_cli = (const float*)d_in[1];
  const int* ct_src = (const int*)d_in[2];
  const int* ct_dst = (const int*)d_in[3];
  const int* tc_src = (const int*)d_in[4];
  const int* tc_dst = (const int*)d_in[5];
  const float* W1ctl = (const float*)d_in[6];
  const float* b1ct  = (const float*)d_in[7];
  const float* W1ctr = (const float*)d_in[8];
  const float* W1tcl = (const float*)d_in[9];
  const float* b1tc  = (const float*)d_in[10];
  const float* W1tcr = (const float*)d_in[11];
  const float* W2ctl = (const float*)d_in[12];
  const float* b2ct  = (const float*)d_in[13];
  const float* W2ctr = (const float*)d_in[14];
  const float* W2tcl = (const float*)d_in[15];
  const float* b2tc  = (const float*)d_in[16];
  const float* W2tcr = (const float*)d_in[17];
  const float* Wd1   = (const float*)d_in[18];
  const float* bd1   = (const float*)d_in[19];
  const float* Wd2   = (const float*)d_in[20];
  const float* bd2   = (const float*)d_in[21];

  const int E = in_sizes[2];  // 600000
  const int NT = 100000, NC = 20000;

  // ---- workspace carve: ~77 MB (< 92.64 MB proven bound) ----
  size_t o = 0;
  auto carve = [&](size_t bytes) {
    void* p = (char*)d_ws + o;
    o = (o + bytes + 255) & ~(size_t)255;
    return p;
  };
  int* deg_ct  = (int*)carve((size_t)NT * 4);
  int* deg_tc  = (int*)carve((size_t)NC * 4);
  size_t zero_bytes = o;  // deg regions only
  int* bsum_ct = (int*)carve(2048);
  int* bsum_tc = (int*)carve(2048);
  int* off_ct = (int*)carve((size_t)(NT + 1) * 4);
  int* off_tc = (int*)carve((size_t)(NC + 1) * 4);
  int* cur_ct = (int*)carve((size_t)NT * 4);
  int* cur_tc = (int*)carve((size_t)NC * 4);
  int* csr_ct = (int*)carve((size_t)E * 4);
  int* csr_tc = (int*)carve((size_t)E * 4);
  ushort* Wt1 = (ushort*)carve((size_t)96 * 128 * 2);
  ushort* Wt2 = (ushort*)carve((size_t)96 * 128 * 2);
  ushort* Wt3 = (ushort*)carve((size_t)256 * 128 * 2);
  ushort* Wt4 = (ushort*)carve((size_t)256 * 128 * 2);
  ushort* Wt5 = (ushort*)carve((size_t)128 * 64 * 2);
  ushort* Wt6 = (ushort*)carve((size_t)64 * 64 * 2);
  bf16* mean1_ct = (bf16*)carve((size_t)NT * 32 * 2);
  bf16* mean1_tc = (bf16*)carve((size_t)NC * 64 * 2);
  bf16* h_txn    = (bf16*)carve((size_t)NT * 128 * 2);
  bf16* h_cli    = (bf16*)carve((size_t)NC * 128 * 2);
  bf16* mean2_ct = (bf16*)carve((size_t)NT * 128 * 2);
  bf16* mean2_tc = (bf16*)carve((size_t)NC * 128 * 2);
  bf16* dec_t = mean2_ct;  // dead by decoder time (12.8 MB <= 25.6 MB)
  (void)ws_size;

  hipMemsetAsync(d_ws, 0, zero_bytes, stream);

  const int tb = 256;
  const int nbE = (E + 255) / 256;
  const int nb_ct = (NT + 255) / 256;  // 391
  const int nb_tc = (NC + 255) / 256;  // 79

  // ---- fused weight transposes (1 launch) ----
  {
    TJobs js;
    auto blocks = [](int k, int ncol) { return (k * ncol + 255) / 256; };
    int boff = 0;
    auto setj = [&](int idx, const float* wl, const float* wr, ushort* dst,
                    int da, int k, int ncol) {
      js.j[idx] = TJob{wl, wr, dst, da, k, ncol, boff};
      boff += blocks(k, ncol);
    };
    setj(0, W1ctl, W1ctr, Wt1, 32, 96, 128);
    setj(1, W1tcl, W1tcr, Wt2, 64, 96, 128);
    setj(2, W2ctl, W2ctr, Wt3, 128, 256, 128);
    setj(3, W2tcl, W2tcr, Wt4, 128, 256, 128);
    setj(4, Wd1, Wd1, Wt5, 128, 128, 64);
    setj(5, Wd2, Wd2, Wt6, 64, 64, 64);
    transpose6_kernel<<<boff, tb, 0, stream>>>(js);
  }

  // ---- CSR build (fused pairs; reused by both layers) ----
  count2_kernel<<<2 * nbE, tb, 0, stream>>>(ct_dst, deg_ct, NT, tc_dst, deg_tc, NC, E, nbE);
  sum_block2_kernel<<<nb_ct + nb_tc, tb, 0, stream>>>(deg_ct, NT, nb_ct, bsum_ct,
                                                      deg_tc, NC, bsum_tc);
  scan_bsum2_kernel<<<2, 1024, 0, stream>>>(bsum_ct, nb_ct, bsum_tc, nb_tc);
  scan_final2_kernel<<<nb_ct + nb_tc, tb, 0, stream>>>(
      deg_ct, bsum_ct, off_ct, cur_ct, NT, nb_ct,
      deg_tc, bsum_tc, off_tc, cur_tc, NC);
  scatter2_kernel<<<2 * nbE, tb, 0, stream>>>(
      ct_src, ct_dst, cur_ct, csr_ct, NT,
      tc_src, tc_dst, cur_tc, csr_tc, NC, E, nbE);

  auto gb64 = [](int n) { return (n + 63) / 64; };

  // ---- layer 1: pull means (fp32 inputs) then fused linears ----
  pull_mean_kernel<32, false><<<(NT + 3) / 4, tb, 0, stream>>>(
      off_ct, csr_ct, x_cli, mean1_ct, NT, NC);
  pull_mean_kernel<64, false><<<(NC + 3) / 4, tb, 0, stream>>>(
      off_tc, csr_tc, x_txn, mean1_tc, NC, NT);

  gemm_kernel<3, 8, 1, AT_BF16, AT_F32, false><<<gb64(NT), tb, 0, stream>>>(
      mean1_ct, 32, x_txn, 64, Wt1, b1ct, h_txn, 0, 128, NT, 1);
  gemm_kernel<3, 8, 2, AT_BF16, AT_F32, false><<<gb64(NC), tb, 0, stream>>>(
      mean1_tc, 64, x_cli, 32, Wt2, b1tc, h_cli, 0, 128, NC, 1);

  // ---- layer 2: pull means (bf16 h) then fused linears ----
  pull_mean_kernel<128, true><<<(NT + 3) / 4, tb, 0, stream>>>(
      off_ct, csr_ct, h_cli, mean2_ct, NT, NC);
  pull_mean_kernel<128, true><<<(NC + 3) / 4, tb, 0, stream>>>(
      off_tc, csr_tc, h_txn, mean2_tc, NC, NT);

  float* out = (float*)d_out;
  const long long ztxn_base = (long long)NT * 64;
  const long long zcli_base = ztxn_base + (long long)NT * 128;

  gemm_kernel<8, 8, 4, AT_BF16, AT_BF16, true><<<gb64(NT), tb, 0, stream>>>(
      mean2_ct, 128, h_txn, 128, Wt3, b2ct, out, ztxn_base, 128, NT, 0);
  gemm_kernel<8, 8, 4, AT_BF16, AT_BF16, true><<<gb64(NC), tb, 0, stream>>>(
      mean2_tc, 128, h_cli, 128, Wt4, b2tc, out, zcli_base, 128, NC, 0);

  // ---- decoder: recon = relu(z @ Wd1 + b) @ Wd2 + b  (z fp32 in d_out) ----
  gemm_kernel<4, 4, 4, AT_F32, AT_F32, false><<<gb64(NT), tb, 0, stream>>>(
      out + ztxn_base, 128, out + ztxn_base, 128, Wt5, bd1, dec_t, 0, 64, NT, 1);
  gemm_kernel<2, 4, 2, AT_BF16, AT_BF16, true><<<gb64(NT), tb, 0, stream>>>(
      dec_t, 64, dec_t, 64, Wt6, bd2, out, 0, 64, NT, 0);
}

// Round 9
// 480.141 us; speedup vs baseline: 4.0122x; 1.1969x over previous
//
#include <hip/hip_runtime.h>
#include <hip/hip_bf16.h>

typedef __hip_bfloat16 bf16;
typedef unsigned int uint;
typedef unsigned short ushort;
typedef __attribute__((ext_vector_type(8))) short short8;   // 8 bf16 = 4 VGPR
typedef __attribute__((ext_vector_type(4))) float float4v;  // MFMA acc

__device__ __forceinline__ float lo2f(uint v) { return __uint_as_float(v << 16); }
__device__ __forceinline__ float hi2f(uint v) { return __uint_as_float(v & 0xffff0000u); }
__device__ __forceinline__ ushort f2bu(float v) {
  union { bf16 h; ushort u; } x;
  x.h = __float2bfloat16(v);
  return x.u;
}
__device__ __forceinline__ uint packbf2(float a, float b) {
  return (uint)f2bu(a) | ((uint)f2bu(b) << 16);
}

#define BSH 8          // bucket shift: 256 nodes per bucket
#define NBK_MAX 391    // max buckets (txn side)

// ======================= fused weight transpose (6 jobs, 1 launch) ===========
struct TJob { const float* wl; const float* wr; ushort* dst; int da, k, ncol, boff; };
struct TJobs { TJob j[6]; };

__global__ void transpose6_kernel(TJobs js) {
  int b = blockIdx.x;
  int jj = 0;
#pragma unroll
  for (int t = 1; t < 6; ++t)
    if (b >= js.j[t].boff) jj = t;
  const TJob J = js.j[jj];
  int i = (b - J.boff) * 256 + threadIdx.x;
  if (i >= J.k * J.ncol) return;
  int k = i / J.ncol, c = i - k * J.ncol;
  const float* srcp = (k < J.da) ? (J.wl + (long long)k * J.ncol)
                                 : (J.wr + (long long)(k - J.da) * J.ncol);
  J.dst[(long long)c * J.k + k] = f2bu(srcp[c]);
}

// ======================= CSR build, two-level counting sort ==================
// Phase 1: coarse histogram of dst>>BSH (LDS per block, atomic merge).
__global__ void bhist_kernel(const int* __restrict__ dA, int* __restrict__ cA, int nbkA,
                             const int* __restrict__ dB, int* __restrict__ cB, int nbkB,
                             int E, int chA) {
  __shared__ int h[NBK_MAX];
  int b = blockIdx.x;
  const int* dst; int* gc; int nbk;
  if (b < chA) { dst = dA; gc = cA; nbk = nbkA; }
  else         { b -= chA; dst = dB; gc = cB; nbk = nbkB; }
  for (int i = threadIdx.x; i < nbk; i += 256) h[i] = 0;
  __syncthreads();
  int e0 = b * 4096;
  for (int j = 0; j < 16; ++j) {
    int e = e0 + j * 256 + threadIdx.x;
    if (e < E) {
      uint B = (uint)dst[e] >> BSH;
      if (B < (uint)nbk) atomicAdd(&h[B], 1);
    }
  }
  __syncthreads();
  for (int i = threadIdx.x; i < nbk; i += 256)
    if (h[i]) atomicAdd(&gc[i], h[i]);
}

// Phase 2: exclusive scan of bucket counts -> bucket offsets + cursors.
__global__ void bscan_kernel(const int* __restrict__ cA, int* __restrict__ oA,
                             int* __restrict__ uA, int nbkA,
                             const int* __restrict__ cB, int* __restrict__ oB,
                             int* __restrict__ uB, int nbkB) {
  __shared__ int s[512];
  const int* cnt; int* off; int* cur; int nbk;
  if (blockIdx.x == 0) { cnt = cA; off = oA; cur = uA; nbk = nbkA; }
  else                 { cnt = cB; off = oB; cur = uB; nbk = nbkB; }
  int t = threadIdx.x;
  int v = (t < nbk) ? cnt[t] : 0;
  s[t] = v;
  __syncthreads();
  for (int o = 1; o < 512; o <<= 1) {
    int x = (t >= o) ? s[t - o] : 0;
    __syncthreads();
    s[t] += x;
    __syncthreads();
  }
  if (t < nbk) { int ex = s[t] - v; off[t] = ex; cur[t] = ex; }
  if (t == nbk - 1) off[nbk] = s[t];
}

// Phase 3: multisplit — scatter (src,dst) into bucket-sorted uint2 array.
// Per-block LDS ranking => per (block,bucket) contiguous write runs.
__global__ void multisplit_kernel(const int* __restrict__ sA, const int* __restrict__ dA,
                                  int* __restrict__ uA, uint2* __restrict__ seA, int nbkA,
                                  const int* __restrict__ sB, const int* __restrict__ dB,
                                  int* __restrict__ uB, uint2* __restrict__ seB, int nbkB,
                                  int E, int chA) {
  __shared__ int cnt[NBK_MAX];
  __shared__ int base[NBK_MAX];
  int b = blockIdx.x;
  const int *src, *dst; int* gcur; uint2* se; int nbk;
  if (b < chA) { src = sA; dst = dA; gcur = uA; se = seA; nbk = nbkA; }
  else         { b -= chA; src = sB; dst = dB; gcur = uB; se = seB; nbk = nbkB; }
  for (int i = threadIdx.x; i < nbk; i += 256) cnt[i] = 0;
  __syncthreads();
  int e0 = b * 4096;
  int mys[16], myd[16], myb[16], myr[16];
#pragma unroll
  for (int j = 0; j < 16; ++j) {
    int e = e0 + j * 256 + threadIdx.x;
    int s = 0, d = 0, bb = -1, r = 0;
    if (e < E) {
      s = src[e]; d = dst[e];
      uint B = (uint)d >> BSH;
      if (B < (uint)nbk) { bb = (int)B; r = atomicAdd(&cnt[bb], 1); }
    }
    mys[j] = s; myd[j] = d; myb[j] = bb; myr[j] = r;
  }
  __syncthreads();
  for (int i = threadIdx.x; i < nbk; i += 256) {
    int c = cnt[i];
    base[i] = c ? atomicAdd(&gcur[i], c) : 0;
  }
  __syncthreads();
#pragma unroll
  for (int j = 0; j < 16; ++j) {
    if (myb[j] >= 0) {
      uint2 v; v.x = (uint)mys[j]; v.y = (uint)myd[j];
      se[base[myb[j]] + myr[j]] = v;
    }
  }
}

// Phase 4: per-bucket fine CSR — one block per bucket, all ranking in LDS.
__global__ void csr_fine_kernel(const uint2* __restrict__ seA, const int* __restrict__ boA,
                                int* __restrict__ offA, int* __restrict__ csrA, int nA, int nbkA,
                                const uint2* __restrict__ seB, const int* __restrict__ boB,
                                int* __restrict__ offB, int* __restrict__ csrB, int nB) {
  __shared__ int s[256];
  __shared__ int cur[256];
  int b = blockIdx.x;
  const uint2* se; const int* bo; int* off; int* csr; int n;
  if (b < nbkA) { se = seA; bo = boA; off = offA; csr = csrA; n = nA; }
  else          { b -= nbkA; se = seB; bo = boB; off = offB; csr = csrB; n = nB; }
  int t = threadIdx.x;
  int ebeg = bo[b], eend = bo[b + 1];
  // local degree histogram
  cur[t] = 0;
  __syncthreads();
  for (int i = ebeg + t; i < eend; i += 256)
    atomicAdd(&cur[se[i].y & 255], 1);
  __syncthreads();
  int v = cur[t];
  s[t] = v;
  __syncthreads();
  for (int o = 1; o < 256; o <<= 1) {
    int x = (t >= o) ? s[t - o] : 0;
    __syncthreads();
    s[t] += x;
    __syncthreads();
  }
  int excl = s[t] - v;
  int node = b * 256 + t;
  if (node < n) off[node] = ebeg + excl;
  if (node == n - 1) off[n] = ebeg + excl + v;
  cur[t] = excl;
  __syncthreads();
  for (int i = ebeg + t; i < eend; i += 256) {
    uint2 e = se[i];
    int pos = ebeg + atomicAdd(&cur[e.y & 255], 1);
    csr[pos] = (int)e.x;
  }
}

// ======================= pull aggregation (mean, bf16 out) — R8-validated ====
template <int D, bool XBF>
__global__ __launch_bounds__(256) void pull_mean_kernel(
    const int* __restrict__ off, const int* __restrict__ csr,
    const void* __restrict__ x, bf16* __restrict__ mean, int n, int nsrc) {
  constexpr int LPR = D / 4;          // lanes per row (4 elems per lane)
  constexpr int PAR = 64 / LPR;       // edges in parallel
  int node = blockIdx.x * 4 + (threadIdx.x >> 6);
  if (node >= n) return;  // wave-uniform
  int lane = threadIdx.x & 63;
  int h = lane / LPR, col = lane % LPR;
  int beg = off[node], deg = off[node + 1] - beg;
  float inv = 1.0f / fmaxf((float)deg, 1.0f);
  float a0 = 0.f, a1 = 0.f, a2 = 0.f, a3 = 0.f;
  for (int i = h; i < deg; i += PAR) {
    int s = csr[beg + i];
    s = ((unsigned)s < (unsigned)nsrc) ? s : 0;
    if (XBF) {
      uint2 v = ((const uint2*)x)[(long long)s * LPR + col];
      a0 += lo2f(v.x); a1 += hi2f(v.x); a2 += lo2f(v.y); a3 += hi2f(v.y);
    } else {
      float4 v = ((const float4*)x)[(long long)s * LPR + col];
      a0 += v.x; a1 += v.y; a2 += v.z; a3 += v.w;
    }
  }
#pragma unroll
  for (int m = LPR; m < 64; m <<= 1) {
    a0 += __shfl_xor(a0, m); a1 += __shfl_xor(a1, m);
    a2 += __shfl_xor(a2, m); a3 += __shfl_xor(a3, m);
  }
  if (h == 0) {
    uint2 o2;
    o2.x = packbf2(a0 * inv, a1 * inv);
    o2.y = packbf2(a2 * inv, a3 * inv);
    ((uint2*)mean)[(long long)node * LPR + col] = o2;
  }
}

// ======================= MFMA GEMM (no LDS, branch-free) — R8-validated ======
#define AT_BF16 0
#define AT_F32  1
template <int KT, int NCT, int K0T, int A0T, int A1T, bool OUTF32>
__global__ __launch_bounds__(256) void gemm_kernel(
    const void* __restrict__ A0, int lda0,
    const void* __restrict__ A1, int lda1,
    const ushort* __restrict__ Wt, const float* __restrict__ bias,
    void* __restrict__ C, long long cbase, int ldc, int n, int relu) {
  constexpr int K = KT * 32;
  int tid = threadIdx.x;
  int wave = tid >> 6, lane = tid & 63;
  int p = lane & 15, q = lane >> 4;
  int rowbase = blockIdx.x * 64 + wave * 16;
  int rcl = min(rowbase + p, n - 1);  // A-load row for this lane

  float4v acc[NCT];
#pragma unroll
  for (int t = 0; t < NCT; ++t) acc[t] = (float4v){0.f, 0.f, 0.f, 0.f};

#pragma unroll
  for (int kt = 0; kt < KT; ++kt) {
    const bool seg0 = (kt < K0T);  // compile-time after unroll
    const void* ab = seg0 ? A0 : A1;
    const int lda = seg0 ? lda0 : lda1;
    const int kof = (seg0 ? kt : (kt - K0T)) * 32;
    const int at = seg0 ? A0T : A1T;
    short8 af;
    {
      long long base = (long long)rcl * lda + kof + q * 8;
      if (at == AT_BF16) {
        af = *(const short8*)((const bf16*)ab + base);
      } else {
        const float* fb = (const float*)ab + base;
        float4 a = *(const float4*)fb;
        float4 b = *(const float4*)(fb + 4);
        short8 r;
        r[0] = (short)f2bu(a.x); r[1] = (short)f2bu(a.y);
        r[2] = (short)f2bu(a.z); r[3] = (short)f2bu(a.w);
        r[4] = (short)f2bu(b.x); r[5] = (short)f2bu(b.y);
        r[6] = (short)f2bu(b.z); r[7] = (short)f2bu(b.w);
        af = r;
      }
    }
#pragma unroll
    for (int t = 0; t < NCT; ++t) {
      int c = t * 16 + p;
      short8 bfr = *(const short8*)(Wt + (long long)c * K + kt * 32 + q * 8);
      acc[t] = __builtin_amdgcn_mfma_f32_16x16x32_bf16(af, bfr, acc[t], 0, 0, 0);
    }
  }

#pragma unroll
  for (int t = 0; t < NCT; ++t) {
    int c = t * 16 + p;
    float bv = bias[c];
#pragma unroll
    for (int r = 0; r < 4; ++r) {
      int row = rowbase + q * 4 + r;
      if (row < n) {
        float v = acc[t][r] + bv;
        if (relu) v = fmaxf(v, 0.f);
        long long idx = cbase + (long long)row * ldc + c;
        if (OUTF32) ((float*)C)[idx] = v;
        else        ((bf16*)C)[idx] = __float2bfloat16(v);
      }
    }
  }
}

// ======================= host ================================================
extern "C" void kernel_launch(void* const* d_in, const int* in_sizes, int n_in,
                              void* d_out, int out_size, void* d_ws,
                              size_t ws_size, hipStream_t stream) {
  const float* x_txn = (const float*)d_in[0];
  const float* x_cli = (const float*)d_in[1];
  const int* ct_src = (const int*)d_in[2];
  const int* ct_dst = (const int*)d_in[3];
  const int* tc_src = (const int*)d_in[4];
  const int* tc_dst = (const int*)d_in[5];
  const float* W1ctl = (const float*)d_in[6];
  const float* b1ct  = (const float*)d_in[7];
  const float* W1ctr = (const float*)d_in[8];
  const float* W1tcl = (const float*)d_in[9];
  const float* b1tc  = (const float*)d_in[10];
  const float* W1tcr = (const float*)d_in[11];
  const float* W2ctl = (const float*)d_in[12];
  const float* b2ct  = (const float*)d_in[13];
  const float* W2ctr = (const float*)d_in[14];
  const float* W2tcl = (const float*)d_in[15];
  const float* b2tc  = (const float*)d_in[16];
  const float* W2tcr = (const float*)d_in[17];
  const float* Wd1   = (const float*)d_in[18];
  const float* bd1   = (const float*)d_in[19];
  const float* Wd2   = (const float*)d_in[20];
  const float* bd2   = (const float*)d_in[21];

  const int E = in_sizes[2];  // 600000
  const int NT = 100000, NC = 20000;
  const int NBK_CT = (NT + 255) >> 8;  // 391
  const int NBK_TC = (NC + 255) >> 8;  // 79

  // ---- workspace carve: ~85.5 MB (< 92.64 MB proven bound) ----
  size_t o = 0;
  auto carve = [&](size_t bytes) {
    void* p = (char*)d_ws + o;
    o = (o + bytes + 255) & ~(size_t)255;
    return p;
  };
  int* bcnt_ct = (int*)carve((size_t)NBK_CT * 4);       // zeroed
  int* bcnt_tc = (int*)carve((size_t)NBK_TC * 4);       // zeroed (same page run)
  size_t zero_bytes = o;
  int* boff_ct = (int*)carve((size_t)(NBK_CT + 1) * 4);
  int* boff_tc = (int*)carve((size_t)(NBK_TC + 1) * 4);
  int* bcur_ct = (int*)carve((size_t)NBK_CT * 4);
  int* bcur_tc = (int*)carve((size_t)NBK_TC * 4);
  uint2* se_ct = (uint2*)carve((size_t)E * 8);
  uint2* se_tc = (uint2*)carve((size_t)E * 8);
  int* off_ct = (int*)carve((size_t)(NT + 1) * 4);
  int* off_tc = (int*)carve((size_t)(NC + 1) * 4);
  int* csr_ct = (int*)carve((size_t)E * 4);
  int* csr_tc = (int*)carve((size_t)E * 4);
  ushort* Wt1 = (ushort*)carve((size_t)96 * 128 * 2);
  ushort* Wt2 = (ushort*)carve((size_t)96 * 128 * 2);
  ushort* Wt3 = (ushort*)carve((size_t)256 * 128 * 2);
  ushort* Wt4 = (ushort*)carve((size_t)256 * 128 * 2);
  ushort* Wt5 = (ushort*)carve((size_t)128 * 64 * 2);
  ushort* Wt6 = (ushort*)carve((size_t)64 * 64 * 2);
  bf16* mean1_ct = (bf16*)carve((size_t)NT * 32 * 2);
  bf16* mean1_tc = (bf16*)carve((size_t)NC * 64 * 2);
  bf16* h_txn    = (bf16*)carve((size_t)NT * 128 * 2);
  bf16* h_cli    = (bf16*)carve((size_t)NC * 128 * 2);
  bf16* mean2_ct = (bf16*)carve((size_t)NT * 128 * 2);
  bf16* mean2_tc = (bf16*)carve((size_t)NC * 128 * 2);
  bf16* dec_t = mean2_ct;  // dead by decoder time (12.8 MB <= 25.6 MB)
  (void)ws_size;

  hipMemsetAsync(d_ws, 0, zero_bytes, stream);

  const int tb = 256;
  const int CH = (E + 4095) / 4096;  // 147 chunks per edge type

  // ---- fused weight transposes (1 launch) ----
  {
    TJobs js;
    auto blocks = [](int k, int ncol) { return (k * ncol + 255) / 256; };
    int boff = 0;
    auto setj = [&](int idx, const float* wl, const float* wr, ushort* dst,
                    int da, int k, int ncol) {
      js.j[idx] = TJob{wl, wr, dst, da, k, ncol, boff};
      boff += blocks(k, ncol);
    };
    setj(0, W1ctl, W1ctr, Wt1, 32, 96, 128);
    setj(1, W1tcl, W1tcr, Wt2, 64, 96, 128);
    setj(2, W2ctl, W2ctr, Wt3, 128, 256, 128);
    setj(3, W2tcl, W2tcr, Wt4, 128, 256, 128);
    setj(4, Wd1, Wd1, Wt5, 128, 128, 64);
    setj(5, Wd2, Wd2, Wt6, 64, 64, 64);
    transpose6_kernel<<<boff, tb, 0, stream>>>(js);
  }

  // ---- CSR build: two-level counting sort (both edge types fused) ----
  bhist_kernel<<<2 * CH, tb, 0, stream>>>(ct_dst, bcnt_ct, NBK_CT,
                                          tc_dst, bcnt_tc, NBK_TC, E, CH);
  bscan_kernel<<<2, 512, 0, stream>>>(bcnt_ct, boff_ct, bcur_ct, NBK_CT,
                                      bcnt_tc, boff_tc, bcur_tc, NBK_TC);
  multisplit_kernel<<<2 * CH, tb, 0, stream>>>(
      ct_src, ct_dst, bcur_ct, se_ct, NBK_CT,
      tc_src, tc_dst, bcur_tc, se_tc, NBK_TC, E, CH);
  csr_fine_kernel<<<NBK_CT + NBK_TC, tb, 0, stream>>>(
      se_ct, boff_ct, off_ct, csr_ct, NT, NBK_CT,
      se_tc, boff_tc, off_tc, csr_tc, NC);

  auto gb64 = [](int n) { return (n + 63) / 64; };

  // ---- layer 1: pull means (fp32 inputs) then fused linears ----
  pull_mean_kernel<32, false><<<(NT + 3) / 4, tb, 0, stream>>>(
      off_ct, csr_ct, x_cli, mean1_ct, NT, NC);
  pull_mean_kernel<64, false><<<(NC + 3) / 4, tb, 0, stream>>>(
      off_tc, csr_tc, x_txn, mean1_tc, NC, NT);

  gemm_kernel<3, 8, 1, AT_BF16, AT_F32, false><<<gb64(NT), tb, 0, stream>>>(
      mean1_ct, 32, x_txn, 64, Wt1, b1ct, h_txn, 0, 128, NT, 1);
  gemm_kernel<3, 8, 2, AT_BF16, AT_F32, false><<<gb64(NC), tb, 0, stream>>>(
      mean1_tc, 64, x_cli, 32, Wt2, b1tc, h_cli, 0, 128, NC, 1);

  // ---- layer 2: pull means (bf16 h) then fused linears ----
  pull_mean_kernel<128, true><<<(NT + 3) / 4, tb, 0, stream>>>(
      off_ct, csr_ct, h_cli, mean2_ct, NT, NC);
  pull_mean_kernel<128, true><<<(NC + 3) / 4, tb, 0, stream>>>(
      off_tc, csr_tc, h_txn, mean2_tc, NC, NT);

  float* out = (float*)d_out;
  const long long ztxn_base = (long long)NT * 64;
  const long long zcli_base = ztxn_base + (long long)NT * 128;

  gemm_kernel<8, 8, 4, AT_BF16, AT_BF16, true><<<gb64(NT), tb, 0, stream>>>(
      mean2_ct, 128, h_txn, 128, Wt3, b2ct, out, ztxn_base, 128, NT, 0);
  gemm_kernel<8, 8, 4, AT_BF16, AT_BF16, true><<<gb64(NC), tb, 0, stream>>>(
      mean2_tc, 128, h_cli, 128, Wt4, b2tc, out, zcli_base, 128, NC, 0);

  // ---- decoder: recon = relu(z @ Wd1 + b) @ Wd2 + b  (z fp32 in d_out) ----
  gemm_kernel<4, 4, 4, AT_F32, AT_F32, false><<<gb64(NT), tb, 0, stream>>>(
      out + ztxn_base, 128, out + ztxn_base, 128, Wt5, bd1, dec_t, 0, 64, NT, 1);
  gemm_kernel<2, 4, 2, AT_BF16, AT_BF16, true><<<gb64(NT), tb, 0, stream>>>(
      dec_t, 64, dec_t, 64, Wt6, bd2, out, 0, 64, NT, 0);
}